// Round 1
// baseline (17673.683 us; speedup 1.0000x reference)
//
#include <hip/hip_runtime.h>

typedef _Float16 f16;
typedef __attribute__((ext_vector_type(8))) _Float16 f16x8;
typedef __attribute__((ext_vector_type(4))) float f32x4;

#define NBATCH 1024
#define NH 1024
#define NT 336
#define NDFF 7
#define NQ 9
#define K0 1088   /* 64 (x padded) + 1024 (h0) */
#define K1 2048   /* 1024 (h0_new) + 1024 (h1) */
#define OUTSTRIDE (NT * NQ)

__device__ __forceinline__ float sigf(float x) { return 1.0f / (1.0f + __expf(-x)); }
__device__ __forceinline__ float tanhfast(float x) { return 1.0f - 2.0f / (__expf(2.0f * x) + 1.0f); }

__device__ __forceinline__ void gll16(const void* g, void* l) {
  __builtin_amdgcn_global_load_lds((const __attribute__((address_space(1))) void*)g,
                                   (__attribute__((address_space(3))) void*)l, 16, 0, 0);
}

// ---------------------------------------------------------------------------
// Packing / init kernels (run every call; deterministic).
// Weight pack layout: Wp[j][k] fp16, rows j = gate output col (i,f,g,o * 1024),
// k pre-swizzled within each 64-col (128B) chunk: dst_k = (k&~63)|((k&63)^((j&7)<<3))
// so staging can read LINEAR and ds_read applies byte XOR ((row&7)<<4).
// ---------------------------------------------------------------------------
__global__ void pack_w0(const float* __restrict__ Wih0, const float* __restrict__ Whh0,
                        f16* __restrict__ Wp0) {
  const int idx = blockIdx.x * 256 + threadIdx.x;
  if (idx >= 4096 * K0) return;
  const int j = idx / K0;
  const int dk = idx - j * K0;
  const int sk = (dk & ~63) | ((dk & 63) ^ ((j & 7) << 3));
  float v;
  if (sk < 8) v = Wih0[j * 8 + sk];          // col 0 = y feedback, 1..7 = features
  else if (sk < 64) v = 0.0f;                // pad
  else v = Whh0[(size_t)j * NH + (sk - 64)];
  Wp0[idx] = (f16)v;
}

__global__ void pack_w1(const float* __restrict__ Wih1, const float* __restrict__ Whh1,
                        f16* __restrict__ Wp1) {
  const int idx = blockIdx.x * 256 + threadIdx.x;  // exactly 4096*2048
  const int j = idx >> 11;
  const int dk = idx & 2047;
  const int sk = (dk & ~63) | ((dk & 63) ^ ((j & 7) << 3));
  const float v = (sk < 1024) ? Wih1[(size_t)j * NH + sk]
                              : Whh1[(size_t)j * NH + (sk - 1024)];
  Wp1[idx] = (f16)v;
}

__global__ void pack_bias(const float* __restrict__ a0, const float* __restrict__ b0,
                          const float* __restrict__ a1, const float* __restrict__ b1,
                          float* __restrict__ bias0, float* __restrict__ bias1) {
  const int j = blockIdx.x * 256 + threadIdx.x;
  if (j < 4096) { bias0[j] = a0[j] + b0[j]; bias1[j] = a1[j] + b1[j]; }
}

// h state stored fp16 pre-swizzled (same chunk swizzle); c stored fp32 plain.
__global__ void init_state(const float* __restrict__ h_in, const float* __restrict__ c_in,
                           f16* __restrict__ h0, f16* __restrict__ h1,
                           float* __restrict__ c0, float* __restrict__ c1) {
  const int idx = blockIdx.x * 256 + threadIdx.x;  // exactly 2*1024*1024
  const int l = idx >> 20;
  const int rc = idx & 1048575;
  const int row = rc >> 10;
  const int dk = idx & 1023;
  const int sk = (dk & ~63) | ((dk & 63) ^ ((row & 7) << 3));
  const float hv = h_in[((size_t)l << 20) + ((size_t)row << 10) + sk];
  if (l == 0) { h0[rc] = (f16)hv; c0[rc] = c_in[idx]; }
  else        { h1[rc] = (f16)hv; c1[rc] = c_in[idx]; }
}

// Sum y partials for the last timestep (t = 335).
__global__ void final_y(const float* __restrict__ ypartT, const float* __restrict__ bout,
                        float* __restrict__ dout) {
  const int idx = blockIdx.x * 256 + threadIdx.x;  // exactly 9216
  const int row = idx & 1023;
  const int q = idx >> 10;
  float s = bout[q];
#pragma unroll
  for (int nb2 = 0; nb2 < 32; ++nb2) s += ypartT[(((q << 5) + nb2) << 10) + row];
  dout[(size_t)row * OUTSTRIDE + 335 * NQ + q] = s;
}

// ---------------------------------------------------------------------------
// Step kernel. IS_S1 = 0: layer 0 (gates0 = [x|h0] @ W0^T), prologue builds the
// x part (y0 feedback from partials + features) and writes y[t-1] outputs.
// IS_S1 = 1: layer 1 (gates1 = [h0_new|h1] @ W1^T), epilogue emits y partials.
// Grid = 256 blocks (1/CU), 128 batch rows x (4 gates x 32 h-cols) per block.
// ---------------------------------------------------------------------------
template <int IS_S1>
__global__ __launch_bounds__(256, 1) void step_kernel(
    const f16* __restrict__ Wp, const float* __restrict__ bias,
    const f16* __restrict__ hA, const f16* __restrict__ hA2,
    float* __restrict__ cbuf, f16* __restrict__ hout,
    const float* __restrict__ ff, const float* __restrict__ inpy,
    float* __restrict__ ypartT, const float* __restrict__ Wout,
    const float* __restrict__ bout, float* __restrict__ dout, int t) {
  constexpr int NKT = IS_S1 ? (K1 / 64) : (K0 / 64);
  constexpr int LDSZ = IS_S1 ? (65536 + 128 * 33 * 4) : 65536;
  __shared__ __align__(16) unsigned char lds8[LDSZ];

  const int tid = threadIdx.x;
  const int wv = tid >> 6;
  const int ln = tid & 63;
  const int blk = blockIdx.x;
  // XCD-aware mapping: XCD (blk&7) owns a 4-colblock stripe across all rowblocks.
  const int rb = (blk >> 3) & 7;
  const int cb = (blk & 7) * 4 + (blk >> 6);
  const int row0 = rb * 128;
  const int hcol0 = cb * 32;

  auto stageB = [&](int kt, int buf) {
#pragma unroll
    for (int i = 0; i < 4; ++i) {
      const int ci = wv * 4 + i;
      const int tr = ci * 8 + (ln >> 3);
      const int j = ((tr >> 5) << 10) + hcol0 + (tr & 31);
      const f16* g = Wp + (size_t)j * (IS_S1 ? K1 : K0) + kt * 64 + (ln & 7) * 8;
      gll16(g, lds8 + buf * 32768 + 16384 + ci * 1024);
    }
  };
  auto stageA = [&](int kt, int buf) {
    const f16* src;
    int kb;
    if (IS_S1) {
      if (kt < 16) { src = hA; kb = kt * 64; }
      else { src = hA2; kb = (kt - 16) * 64; }
    } else { src = hA; kb = (kt - 1) * 64; }
#pragma unroll
    for (int i = 0; i < 4; ++i) {
      const int ci = wv * 4 + i;
      const int r = ci * 8 + (ln >> 3);
      const f16* g = src + (size_t)(row0 + r) * NH + kb + (ln & 7) * 8;
      gll16(g, lds8 + buf * 32768 + ci * 1024);
    }
  };

  // ---- prologue: stage k-tile 0 into buf0 ----
  if (!IS_S1) {
    if (tid < 128) {
      const int row = row0 + tid;
      float y0;
      if (t == 0) {
        y0 = inpy[row];
      } else {
        y0 = bout[0];
        const float* yp = ypartT + row;  // ypartT[0][nb2][row]
#pragma unroll
        for (int nb2 = 0; nb2 < 32; ++nb2) y0 += yp[nb2 << 10];
      }
      const float* fsrc = ff + ((size_t)row * NT + t) * NDFF;
      f16x8 xv;
      xv[0] = (f16)y0;
#pragma unroll
      for (int jj = 0; jj < 7; ++jj) xv[1 + jj] = (f16)fsrc[jj];
      *(f16x8*)(lds8 + tid * 128 + ((tid & 7) << 4)) = xv;  // chunk 0, swizzled
    }
    f16x8 zv;
#pragma unroll
    for (int jj = 0; jj < 8; ++jj) zv[jj] = (f16)0.0f;
    for (int idx = tid; idx < 128 * 7; idx += 256) {
      const int r = idx / 7;
      const int ch = 1 + (idx - r * 7);
      *(f16x8*)(lds8 + r * 128 + ((ch ^ (r & 7)) << 4)) = zv;  // zero pad k=8..63
    }
    // write y[t-1] output: colblocks 0..8 each own one q
    if (t > 0 && cb < NQ && tid < 128) {
      const int q = cb;
      const int row = row0 + tid;
      float s = bout[q];
      const float* yp = ypartT + ((size_t)(q << 5) << 10) + row;
#pragma unroll
      for (int nb2 = 0; nb2 < 32; ++nb2) s += yp[nb2 << 10];
      dout[(size_t)row * OUTSTRIDE + (t - 1) * NQ + q] = s;
    }
    stageB(0, 0);
  } else {
    stageA(0, 0);
    stageB(0, 0);
  }
  __syncthreads();

  // ---- main K loop: double-buffered, stage(kt+1) issued before compute(kt) ----
  f32x4 acc[2][8];
  const f32x4 zf = {0.0f, 0.0f, 0.0f, 0.0f};
#pragma unroll
  for (int m = 0; m < 2; ++m)
#pragma unroll
    for (int n = 0; n < 8; ++n) acc[m][n] = zf;

  const int lanerow = ln & 15;
  const int xm = (ln & 7) << 4;           // swizzle mask
  const int kgrp = (ln >> 4) << 4;        // byte base: (lane/16)*8 halves

  for (int kt = 0; kt < NKT; ++kt) {
    const int bcur = kt & 1;
    if (kt + 1 < NKT) { stageA(kt + 1, bcur ^ 1); stageB(kt + 1, bcur ^ 1); }
    const unsigned char* Ab = lds8 + bcur * 32768;
    const unsigned char* Bb = Ab + 16384;
#pragma unroll
    for (int ks = 0; ks < 2; ++ks) {
      const int kb = (kgrp + ks * 64) ^ xm;
      f16x8 afr[2], bfr[8];
#pragma unroll
      for (int m = 0; m < 2; ++m)
        afr[m] = *(const f16x8*)(Ab + (wv * 32 + m * 16 + lanerow) * 128 + kb);
#pragma unroll
      for (int n = 0; n < 8; ++n)
        bfr[n] = *(const f16x8*)(Bb + (n * 16 + lanerow) * 128 + kb);
#pragma unroll
      for (int m = 0; m < 2; ++m)
#pragma unroll
        for (int n = 0; n < 8; ++n)
          acc[m][n] = __builtin_amdgcn_mfma_f32_16x16x32_f16(afr[m], bfr[n], acc[m][n], 0, 0, 0);
    }
    __syncthreads();
  }

  // ---- epilogue: LSTM cell update (register-local; i,f,g,o tiles co-resident) ----
  float* hbuf = (float*)(lds8 + 65536);  // S1 only
#pragma unroll
  for (int m = 0; m < 2; ++m) {
#pragma unroll
    for (int hs = 0; hs < 2; ++hs) {
      const int hcol = hcol0 + hs * 16 + lanerow;
      const float bi = bias[hcol];
      const float bf = bias[NH + hcol];
      const float bg = bias[2 * NH + hcol];
      const float bo = bias[3 * NH + hcol];
      const f32x4 vi = acc[m][0 + hs];
      const f32x4 vf = acc[m][2 + hs];
      const f32x4 vg = acc[m][4 + hs];
      const f32x4 vo = acc[m][6 + hs];
#pragma unroll
      for (int r = 0; r < 4; ++r) {
        const int rloc = wv * 32 + m * 16 + ((ln >> 4) << 2) + r;
        const int row = row0 + rloc;
        const size_t cidx = (size_t)row * NH + hcol;
        const float c_old = cbuf[cidx];
        const float ig = sigf(vi[r] + bi);
        const float fg = sigf(vf[r] + bf);
        const float gg = tanhfast(vg[r] + bg);
        const float og = sigf(vo[r] + bo);
        const float cn = fg * c_old + ig * gg;
        const float hn = og * tanhfast(cn);
        cbuf[cidx] = cn;
        const int cc2 = (hcol & 63) << 1;
        *(f16*)((unsigned char*)hout + (size_t)row * 2048 + ((hcol >> 6) << 7) +
                (cc2 ^ ((row & 7) << 4))) = (f16)hn;  // swizzled fp16 h store
        if (IS_S1) hbuf[rloc * 33 + hs * 16 + lanerow] = hn;
      }
    }
  }
  if (IS_S1) {
    __syncthreads();
    // y partials over this block's 32 h-cols: ypartT[q][cb][row] (coalesced)
    for (int task = tid; task < 128 * NQ; task += 256) {
      const int rloc = task & 127;
      const int q = task >> 7;
      const float* wq = Wout + q * NH + hcol0;
      float s = 0.0f;
#pragma unroll
      for (int c2 = 0; c2 < 32; ++c2) s += hbuf[rloc * 33 + c2] * wq[c2];
      ypartT[(size_t)((q << 5) + cb) * 1024 + row0 + rloc] = s;
    }
  }
}

// ---------------------------------------------------------------------------
extern "C" void kernel_launch(void* const* d_in, const int* in_sizes, int n_in,
                              void* d_out, int out_size, void* d_ws, size_t ws_size,
                              hipStream_t stream) {
  const float* inpy = (const float*)d_in[2];
  const float* h_in = (const float*)d_in[3];
  const float* c_in = (const float*)d_in[4];
  const float* ff   = (const float*)d_in[5];
  const float* Wih0 = (const float*)d_in[9];
  const float* Whh0 = (const float*)d_in[10];
  const float* bih0 = (const float*)d_in[11];
  const float* bhh0 = (const float*)d_in[12];
  const float* Wih1 = (const float*)d_in[13];
  const float* Whh1 = (const float*)d_in[14];
  const float* bih1 = (const float*)d_in[15];
  const float* bhh1 = (const float*)d_in[16];
  const float* Wout = (const float*)d_in[17];
  const float* bout = (const float*)d_in[18];
  float* dout = (float*)d_out;

  unsigned char* ws = (unsigned char*)d_ws;
  size_t off = 0;
  auto alloc = [&](size_t bytes) -> void* {
    void* p = ws + off;
    off += (bytes + 255) & ~(size_t)255;
    return p;
  };
  f16* Wp0 = (f16*)alloc((size_t)4096 * K0 * 2);
  f16* Wp1 = (f16*)alloc((size_t)4096 * K1 * 2);
  f16* h0b0 = (f16*)alloc((size_t)NBATCH * NH * 2);
  f16* h0b1 = (f16*)alloc((size_t)NBATCH * NH * 2);
  f16* h1b0 = (f16*)alloc((size_t)NBATCH * NH * 2);
  f16* h1b1 = (f16*)alloc((size_t)NBATCH * NH * 2);
  float* c0 = (float*)alloc((size_t)NBATCH * NH * 4);
  float* c1 = (float*)alloc((size_t)NBATCH * NH * 4);
  float* bias0 = (float*)alloc(4096 * 4);
  float* bias1 = (float*)alloc(4096 * 4);
  float* ypartT = (float*)alloc((size_t)NQ * 32 * 1024 * 4);
  f16* h0b[2] = {h0b0, h0b1};
  f16* h1b[2] = {h1b0, h1b1};

  pack_w0<<<(4096 * K0) / 256, 256, 0, stream>>>(Wih0, Whh0, Wp0);
  pack_w1<<<(4096 * K1) / 256, 256, 0, stream>>>(Wih1, Whh1, Wp1);
  pack_bias<<<16, 256, 0, stream>>>(bih0, bhh0, bih1, bhh1, bias0, bias1);
  init_state<<<(2 * NBATCH * NH) / 256, 256, 0, stream>>>(h_in, c_in, h0b[0], h1b[0], c0, c1);

  for (int t = 0; t < NT; ++t) {
    const int p = t & 1;
    // layer 0: reads h0[p], writes h0[1-p]; also sums y[t-1] from partials
    step_kernel<0><<<256, 256, 0, stream>>>(Wp0, bias0, h0b[p], nullptr, c0, h0b[1 - p],
                                            ff, inpy, ypartT, nullptr, bout, dout, t);
    // layer 1: A = [h0_new | h1[p]], writes h1[1-p] + y partials
    step_kernel<1><<<256, 256, 0, stream>>>(Wp1, bias1, h0b[1 - p], h1b[p], c1, h1b[1 - p],
                                            nullptr, nullptr, ypartT, Wout, bout, dout, t);
  }
  final_y<<<36, 256, 0, stream>>>(ypartT, bout, dout);
}

// Round 2
// 15054.532 us; speedup vs baseline: 1.1740x; 1.1740x over previous
//
#include <hip/hip_runtime.h>

typedef _Float16 f16;
typedef __attribute__((ext_vector_type(8))) _Float16 f16x8;
typedef __attribute__((ext_vector_type(4))) float f32x4;

#define NBATCH 1024
#define NH 1024
#define NT 336
#define NDFF 7
#define NQ 9
#define K0 1088   /* 64 (x padded) + 1024 (h0) */
#define K1 2048   /* 1024 (h0_new) + 1024 (h1) */
#define OUTSTRIDE (NT * NQ)

__device__ __forceinline__ float sigf(float x) { return 1.0f / (1.0f + __expf(-x)); }
__device__ __forceinline__ float tanhfast(float x) { return 1.0f - 2.0f / (__expf(2.0f * x) + 1.0f); }

__device__ __forceinline__ void gll16(const void* g, void* l) {
  __builtin_amdgcn_global_load_lds((const __attribute__((address_space(1))) void*)g,
                                   (__attribute__((address_space(3))) void*)l, 16, 0, 0);
}

// ---------------------------------------------------------------------------
// Weight pack: rows permuted so LDS B-tile row p (0..127 within colblock cb):
//   gate = (p>>4)&3, hcol_local = (p>>6)*16 + (p&15)
// => wave wc (0/1) owns rows [wc*64, wc*64+64) = 16 hcols x ALL 4 gates, and
// MFMA n-frag index IS the gate => register-local cell update per thread.
// k pre-swizzled within each 64-col chunk: dst_k = (k&~63)|((k&63)^((p&7)<<3))
// so staging reads LINEAR and ds_read applies byte XOR ((lds_row&7)<<4).
// ---------------------------------------------------------------------------
__global__ void pack_w0(const float* __restrict__ Wih0, const float* __restrict__ Whh0,
                        f16* __restrict__ Wp0) {
  const int idx = blockIdx.x * 256 + threadIdx.x;  // exactly 4096*K0
  const int pr = idx / K0;
  const int dk = idx - pr * K0;
  const int cb = pr >> 7, p = pr & 127;
  const int gate = (p >> 4) & 3;
  const int hl = ((p >> 6) << 4) | (p & 15);
  const int j = (gate << 10) + (cb << 5) + hl;
  const int sk = (dk & ~63) | ((dk & 63) ^ ((p & 7) << 3));
  float v;
  if (sk < 8) v = Wih0[j * 8 + sk];          // col 0 = y feedback, 1..7 = features
  else if (sk < 64) v = 0.0f;                // pad
  else v = Whh0[(size_t)j * NH + (sk - 64)];
  Wp0[idx] = (f16)v;
}

__global__ void pack_w1(const float* __restrict__ Wih1, const float* __restrict__ Whh1,
                        f16* __restrict__ Wp1) {
  const int idx = blockIdx.x * 256 + threadIdx.x;  // exactly 4096*2048
  const int pr = idx >> 11;
  const int dk = idx & 2047;
  const int cb = pr >> 7, p = pr & 127;
  const int gate = (p >> 4) & 3;
  const int hl = ((p >> 6) << 4) | (p & 15);
  const int j = (gate << 10) + (cb << 5) + hl;
  const int sk = (dk & ~63) | ((dk & 63) ^ ((p & 7) << 3));
  const float v = (sk < 1024) ? Wih1[(size_t)j * NH + sk]
                              : Whh1[(size_t)j * NH + (sk - 1024)];
  Wp1[idx] = (f16)v;
}

__global__ void pack_bias(const float* __restrict__ a0, const float* __restrict__ b0,
                          const float* __restrict__ a1, const float* __restrict__ b1,
                          float* __restrict__ bias0, float* __restrict__ bias1) {
  const int j = blockIdx.x * 256 + threadIdx.x;
  if (j < 4096) { bias0[j] = a0[j] + b0[j]; bias1[j] = a1[j] + b1[j]; }
}

// h state stored fp16 pre-swizzled (chunk swizzle keyed by row&7); c fp32 plain.
__global__ void init_state(const float* __restrict__ h_in, const float* __restrict__ c_in,
                           f16* __restrict__ h0, f16* __restrict__ h1,
                           float* __restrict__ c0, float* __restrict__ c1) {
  const int idx = blockIdx.x * 256 + threadIdx.x;  // exactly 2*1024*1024
  const int l = idx >> 20;
  const int rc = idx & 1048575;
  const int row = rc >> 10;
  const int dk = idx & 1023;
  const int sk = (dk & ~63) | ((dk & 63) ^ ((row & 7) << 3));
  const float hv = h_in[((size_t)l << 20) + ((size_t)row << 10) + sk];
  if (l == 0) { h0[rc] = (f16)hv; c0[rc] = c_in[idx]; }
  else        { h1[rc] = (f16)hv; c1[rc] = c_in[idx]; }
}

// Sum y partials for the last timestep (t = 335).
__global__ void final_y(const float* __restrict__ ypartT, const float* __restrict__ bout,
                        float* __restrict__ dout) {
  const int idx = blockIdx.x * 256 + threadIdx.x;  // exactly 9216
  const int row = idx & 1023;
  const int q = idx >> 10;
  float s = bout[q];
#pragma unroll
  for (int nb2 = 0; nb2 < 32; ++nb2) s += ypartT[(((q << 5) + nb2) << 10) + row];
  dout[(size_t)row * OUTSTRIDE + 335 * NQ + q] = s;
}

// ---------------------------------------------------------------------------
// Step kernel: 128(M batch) x 128(N = 4 gates x 32 hcols) tile per block,
// grid 256 (1/CU), 4 waves tiled 2x2 (64x64 each), K pipelined 3-deep:
//   per iter: [sched_fence; s_waitcnt vmcnt(8); s_barrier; sched_fence]
//             issue stage(kt+2) -> buf (kt+2)%3; ds_read + 32 MFMA on buf kt%3.
// Safety: crossing barrier_kt certifies (1) every wave's stage(kt) landed
// (each waited vmcnt(8) with only stage(kt+1) newer outstanding — vmcnt
// retires in order) and (2) every wave finished ds_reads of tile kt-1
// (program order + lgkm drained before its MFMAs), so stage(kt+2) may
// overwrite buf (kt-1)%3.
// ---------------------------------------------------------------------------
template <int IS_S1>
__global__ __launch_bounds__(256, 1) void step_kernel(
    const f16* __restrict__ Wp, const float* __restrict__ bias,
    const f16* __restrict__ hA, const f16* __restrict__ hA2,
    float* __restrict__ cbuf, f16* __restrict__ hout,
    const float* __restrict__ ff, const float* __restrict__ inpy,
    float* __restrict__ ypartT, const float* __restrict__ Wout,
    const float* __restrict__ bout, float* __restrict__ dout, int t) {
  constexpr int KDIM = IS_S1 ? K1 : K0;
  constexpr int NKT = KDIM / 64;
  constexpr int LDSZ = IS_S1 ? (98304 + 128 * 33 * 4) : 98304;
  __shared__ __align__(16) unsigned char lds8[LDSZ];

  const int tid = threadIdx.x;
  const int wv = tid >> 6;
  const int ln = tid & 63;
  const int wr = wv >> 1, wc = wv & 1;
  const int blk = blockIdx.x;
  // XCD-aware mapping: XCD (blk&7) owns a 4-colblock stripe across all rowblocks
  // => per-XCD weight working set ~3 MB, L2-resident across the whole run.
  const int rb = (blk >> 3) & 7;
  const int cb = (blk & 7) * 4 + (blk >> 6);
  const int row0 = rb * 128;
  const int hcol0 = cb * 32;

  auto stageB = [&](int kt, int buf) {
#pragma unroll
    for (int i = 0; i < 4; ++i) {
      const int ci = wv * 4 + i;
      const int tr = ci * 8 + (ln >> 3);
      const f16* g = Wp + (size_t)(cb * 128 + tr) * KDIM + kt * 64 + (ln & 7) * 8;
      gll16(g, lds8 + buf * 32768 + 16384 + ci * 1024);
    }
  };
  auto stageA = [&](int kt, int buf) {
    const f16* src;
    int kb;
    if (IS_S1) {
      if (kt < 16) { src = hA; kb = kt * 64; }
      else { src = hA2; kb = (kt - 16) * 64; }
    } else { src = hA; kb = (kt - 1) * 64; }
#pragma unroll
    for (int i = 0; i < 4; ++i) {
      const int ci = wv * 4 + i;
      const int r = ci * 8 + (ln >> 3);
      const f16* g = src + (size_t)(row0 + r) * NH + kb + (ln & 7) * 8;
      gll16(g, lds8 + buf * 32768 + ci * 1024);
    }
  };

  // ---- prologue ----
  if (!IS_S1) {
    if (tid < 128) {
      const int row = row0 + tid;
      float y0;
      if (t == 0) {
        y0 = inpy[row];
      } else {
        y0 = bout[0];
        const float* yp = ypartT + row;  // ypartT[0][nb2][row]
#pragma unroll
        for (int nb2 = 0; nb2 < 32; ++nb2) y0 += yp[nb2 << 10];
      }
      const float* fsrc = ff + ((size_t)row * NT + t) * NDFF;
      f16x8 xv;
      xv[0] = (f16)y0;
#pragma unroll
      for (int jj = 0; jj < 7; ++jj) xv[1 + jj] = (f16)fsrc[jj];
      *(f16x8*)(lds8 + tid * 128 + ((tid & 7) << 4)) = xv;  // chunk 0, swizzled
    }
    f16x8 zv;
#pragma unroll
    for (int jj = 0; jj < 8; ++jj) zv[jj] = (f16)0.0f;
    for (int idx = tid; idx < 128 * 7; idx += 256) {
      const int r = idx / 7;
      const int ch = 1 + (idx - r * 7);
      *(f16x8*)(lds8 + r * 128 + ((ch ^ (r & 7)) << 4)) = zv;  // zero pad k=8..63
    }
    // write y[t-1] output: colblocks 0..8 each own one q
    if (t > 0 && cb < NQ && tid < 128) {
      const int q = cb;
      const int row = row0 + tid;
      float s = bout[q];
      const float* yp = ypartT + ((size_t)(q << 5) << 10) + row;
#pragma unroll
      for (int nb2 = 0; nb2 < 32; ++nb2) s += yp[nb2 << 10];
      dout[(size_t)row * OUTSTRIDE + (t - 1) * NQ + q] = s;
    }
    stageB(0, 0);          // buf0 A built above via ds_write (4 gll16 here)
    stageA(1, 1); stageB(1, 1);
  } else {
    stageA(0, 0); stageB(0, 0);
    stageA(1, 1); stageB(1, 1);
  }
  asm volatile("s_waitcnt lgkmcnt(0)" ::: "memory");  // x-build ds_writes visible

  // ---- main K loop ----
  f32x4 acc[4][4];
  const f32x4 zf = {0.0f, 0.0f, 0.0f, 0.0f};
#pragma unroll
  for (int m = 0; m < 4; ++m)
#pragma unroll
    for (int n = 0; n < 4; ++n) acc[m][n] = zf;

  const int lanerow = ln & 15;
  const int xm = (ln & 7) << 4;           // read-side swizzle (== (lds_row&7)<<4)
  const int kgrp = (ln >> 4) << 4;        // fragment k-group byte base
  int bc = 0;                              // kt % 3

  for (int kt = 0; kt < NKT; ++kt) {
    __builtin_amdgcn_sched_barrier(0);
    if (kt + 1 < NKT) {
      asm volatile("s_waitcnt vmcnt(8)" ::: "memory");   // stage(kt) landed
    } else {
      asm volatile("s_waitcnt vmcnt(0)" ::: "memory");
    }
    __builtin_amdgcn_s_barrier();
    __builtin_amdgcn_sched_barrier(0);
    if (kt + 2 < NKT) {
      const int nb = (bc == 0) ? 2 : bc - 1;  // (kt+2)%3
      stageA(kt + 2, nb);
      stageB(kt + 2, nb);
    }
    const unsigned char* Ab = lds8 + bc * 32768;
    const unsigned char* Bb = Ab + 16384;
#pragma unroll
    for (int ks = 0; ks < 2; ++ks) {
      const int kb = (kgrp + ks * 64) ^ xm;
      f16x8 afr[4], bfr[4];
#pragma unroll
      for (int m = 0; m < 4; ++m)
        afr[m] = *(const f16x8*)(Ab + (wr * 64 + m * 16 + lanerow) * 128 + kb);
#pragma unroll
      for (int n = 0; n < 4; ++n)
        bfr[n] = *(const f16x8*)(Bb + (wc * 64 + n * 16 + lanerow) * 128 + kb);
      __builtin_amdgcn_s_setprio(1);
#pragma unroll
      for (int m = 0; m < 4; ++m)
#pragma unroll
        for (int n = 0; n < 4; ++n)
          acc[m][n] = __builtin_amdgcn_mfma_f32_16x16x32_f16(afr[m], bfr[n], acc[m][n], 0, 0, 0);
      __builtin_amdgcn_s_setprio(0);
    }
    bc = (bc == 2) ? 0 : bc + 1;
  }

  // ---- epilogue: LSTM cell update (i,f,g,o = acc[m][0..3], register-local) ----
  float* hbuf = (float*)(lds8 + 98304);  // S1 only
  const int hcol = hcol0 + wc * 16 + lanerow;
  const float bi = bias[hcol];
  const float bff = bias[NH + hcol];
  const float bg = bias[2 * NH + hcol];
  const float bo = bias[3 * NH + hcol];
#pragma unroll
  for (int m = 0; m < 4; ++m) {
    const f32x4 vi = acc[m][0];
    const f32x4 vf = acc[m][1];
    const f32x4 vg = acc[m][2];
    const f32x4 vo = acc[m][3];
#pragma unroll
    for (int r = 0; r < 4; ++r) {
      const int rloc = wr * 64 + m * 16 + ((ln >> 4) << 2) + r;
      const int row = row0 + rloc;
      const size_t cidx = (size_t)row * NH + hcol;
      const float c_old = cbuf[cidx];
      const float ig = sigf(vi[r] + bi);
      const float fg = sigf(vf[r] + bff);
      const float gg = tanhfast(vg[r] + bg);
      const float og = sigf(vo[r] + bo);
      const float cn = fg * c_old + ig * gg;
      const float hn = og * tanhfast(cn);
      cbuf[cidx] = cn;
      *(f16*)((unsigned char*)hout + (size_t)row * 2048 + ((hcol >> 6) << 7) +
              (((hcol & 63) << 1) ^ ((row & 7) << 4))) = (f16)hn;  // swizzled h
      if (IS_S1) hbuf[rloc * 33 + wc * 16 + lanerow] = hn;
    }
  }
  if (IS_S1) {
    __syncthreads();
    // y partials over this block's 32 h-cols: ypartT[q][cb][row] (coalesced)
    for (int task = tid; task < 128 * NQ; task += 256) {
      const int rloc = task & 127;
      const int q = task >> 7;
      const float* wq = Wout + q * NH + hcol0;
      float s = 0.0f;
#pragma unroll
      for (int c2 = 0; c2 < 32; ++c2) s += hbuf[rloc * 33 + c2] * wq[c2];
      ypartT[(size_t)((q << 5) + cb) * 1024 + row0 + rloc] = s;
    }
  }
}

// ---------------------------------------------------------------------------
extern "C" void kernel_launch(void* const* d_in, const int* in_sizes, int n_in,
                              void* d_out, int out_size, void* d_ws, size_t ws_size,
                              hipStream_t stream) {
  const float* inpy = (const float*)d_in[2];
  const float* h_in = (const float*)d_in[3];
  const float* c_in = (const float*)d_in[4];
  const float* ff   = (const float*)d_in[5];
  const float* Wih0 = (const float*)d_in[9];
  const float* Whh0 = (const float*)d_in[10];
  const float* bih0 = (const float*)d_in[11];
  const float* bhh0 = (const float*)d_in[12];
  const float* Wih1 = (const float*)d_in[13];
  const float* Whh1 = (const float*)d_in[14];
  const float* bih1 = (const float*)d_in[15];
  const float* bhh1 = (const float*)d_in[16];
  const float* Wout = (const float*)d_in[17];
  const float* bout = (const float*)d_in[18];
  float* dout = (float*)d_out;

  unsigned char* ws = (unsigned char*)d_ws;
  size_t off = 0;
  auto alloc = [&](size_t bytes) -> void* {
    void* p = ws + off;
    off += (bytes + 255) & ~(size_t)255;
    return p;
  };
  f16* Wp0 = (f16*)alloc((size_t)4096 * K0 * 2);
  f16* Wp1 = (f16*)alloc((size_t)4096 * K1 * 2);
  f16* h0b0 = (f16*)alloc((size_t)NBATCH * NH * 2);
  f16* h0b1 = (f16*)alloc((size_t)NBATCH * NH * 2);
  f16* h1b0 = (f16*)alloc((size_t)NBATCH * NH * 2);
  f16* h1b1 = (f16*)alloc((size_t)NBATCH * NH * 2);
  float* c0 = (float*)alloc((size_t)NBATCH * NH * 4);
  float* c1 = (float*)alloc((size_t)NBATCH * NH * 4);
  float* bias0 = (float*)alloc(4096 * 4);
  float* bias1 = (float*)alloc(4096 * 4);
  float* ypartT = (float*)alloc((size_t)NQ * 32 * 1024 * 4);
  f16* h0b[2] = {h0b0, h0b1};
  f16* h1b[2] = {h1b0, h1b1};

  pack_w0<<<(4096 * K0) / 256, 256, 0, stream>>>(Wih0, Whh0, Wp0);
  pack_w1<<<(4096 * K1) / 256, 256, 0, stream>>>(Wih1, Whh1, Wp1);
  pack_bias<<<16, 256, 0, stream>>>(bih0, bhh0, bih1, bhh1, bias0, bias1);
  init_state<<<(2 * NBATCH * NH) / 256, 256, 0, stream>>>(h_in, c_in, h0b[0], h1b[0], c0, c1);

  for (int t = 0; t < NT; ++t) {
    const int p = t & 1;
    step_kernel<0><<<256, 256, 0, stream>>>(Wp0, bias0, h0b[p], nullptr, c0, h0b[1 - p],
                                            ff, inpy, ypartT, nullptr, bout, dout, t);
    step_kernel<1><<<256, 256, 0, stream>>>(Wp1, bias1, h0b[1 - p], h1b[p], c1, h1b[1 - p],
                                            nullptr, nullptr, ypartT, Wout, bout, dout, t);
  }
  final_y<<<36, 256, 0, stream>>>(ypartT, bout, dout);
}